// Round 9
// baseline (182.020 us; speedup 1.0000x reference)
//
#include <hip/hip_runtime.h>
#include <stdint.h>

#define N_CAND 462080   // 16*76*76*5
#define NBINS  8192
#define HIST_BLOCKS 32
#define TARGET 256u
#define SMAX   1024
#define SCORE_THR 0.02f
#define CPB 1024
#define COMPACT_BLOCKS ((N_CAND + CPB - 1) / CPB)   // 452

// ---------------- ws layout (bytes) ----------------
// ctrl      : 8 x u32        @ 0       [0]=compact count [1]=cutoff bin
//                                      [2]=hist done     [3]=compact done
// hist_part : 32 x 8192 u16  @ 256     end 524544
// lscore    : 1024 x f32     @ 524544  end 528640
// lidx      : 1024 x i32     @ 528640  end 532736
// scores    : N x f32        @ 532736  end 2381056
// cls       : N x u8         @ 2381056 end 2843136  (~2.85 MB)
// No memset dispatch: decode block 0 re-arms ctrl[2]/ctrl[3] every call;
// hist's last block zeroes ctrl[0]; ctrl[1] is written on every path.
// => no dependence on initial ws content (harness poisons ws to 0xAA).

typedef const __attribute__((address_space(1))) uint32_t* gas1_u32;
typedef __attribute__((address_space(3))) uint32_t*       las3_u32;
#define GLOAD_LDS16(g, l) __builtin_amdgcn_global_load_lds( \
    (gas1_u32)(const void*)(g), (las3_u32)(void*)(l), 16, 0, 0)

// ============ Kernel 1: decode — one wave per block, no barriers ============
__global__ __launch_bounds__(64) void decode_kernel(
    const float* __restrict__ feats,
    float* __restrict__ scores, unsigned char* __restrict__ cls,
    unsigned int* __restrict__ ctrl)
{
    __shared__ __align__(16) float lds[64 * 85];   // 21760 B -> 7 blocks/CU
    const int t = threadIdx.x;                     // 0..63 (one wave)
    const long long base = (long long)blockIdx.x * 64;

    if (blockIdx.x == 0 && t == 0) { ctrl[2] = 0u; ctrl[3] = 0u; }  // re-arm done counters

    // 64*85 floats = 1360 float4; 21 full wave-rounds + 16-lane tail.
    const float4* __restrict__ src = (const float4*)(feats + base * 85);
    float4* dst = (float4*)lds;
#pragma unroll
    for (int i = 0; i < 21; ++i)
        GLOAD_LDS16(src + i * 64 + t, dst + i * 64 + t);
    if (t < 16) GLOAD_LDS16(src + 21 * 64 + t, dst + 21 * 64 + t);

    asm volatile("s_waitcnt vmcnt(0)" ::: "memory");   // per-wave drain, no barrier
    __builtin_amdgcn_sched_barrier(0);

    const float* f = lds + t * 85;   // bank (t*21+k)%32: gcd(21,32)=1 -> conflict-free
    const int ci = (int)base + t;

    // class argmax over raw logits (== argmax of softmax, first-index ties)
    float m = f[5];
    int cbest = 0;
#pragma unroll
    for (int k = 1; k < 80; ++k) {
        float v = f[5 + k];
        if (v > m) { m = v; cbest = k; }
    }
    // softmax max-prob = 1 / sum(exp(l - m))
    float s0 = 0.f, s1 = 0.f, s2 = 0.f, s3 = 0.f;
#pragma unroll
    for (int k = 0; k < 80; k += 4) {
        s0 += __expf(f[5 + k] - m);
        s1 += __expf(f[6 + k] - m);
        s2 += __expf(f[7 + k] - m);
        s3 += __expf(f[8 + k] - m);
    }
    float ssum = (s0 + s1) + (s2 + s3);
    float conf = 1.0f / (1.0f + __expf(-f[4]));
    float score = conf * (1.0f / ssum);

    cls[ci] = (unsigned char)cbest;
    scores[ci] = (score >= SCORE_THR) ? score : -1.0f;
}

// ============ Kernel 2: histogram + (last block) cutoff scan ============
__global__ __launch_bounds__(1024) void hist_cutoff_kernel(
    const float* __restrict__ scores, unsigned short* __restrict__ hist_part,
    unsigned int* __restrict__ ctrl)
{
    __shared__ unsigned int lh[NBINS];          // 32 KB
    __shared__ unsigned int pa[1024], pb[1024]; // 8 KB ping-pong (cutoff phase)
    __shared__ int lastf;
    const int t = threadIdx.x;

#pragma unroll
    for (int i = 0; i < 8; ++i) lh[t * 8 + i] = 0u;
    __syncthreads();

    for (int i = blockIdx.x * 1024 + t; i < N_CAND; i += HIST_BLOCKS * 1024) {
        float s = scores[i];
        if (s >= SCORE_THR) {
            int bin = (int)(s * (float)NBINS);
            bin = bin > (NBINS - 1) ? (NBINS - 1) : bin;
            atomicAdd(&lh[bin], 1u);   // LDS atomic only
        }
    }
    __syncthreads();
    unsigned short* outp = hist_part + (size_t)blockIdx.x * NBINS;
#pragma unroll
    for (int i = 0; i < 8; ++i)
        outp[t * 8 + i] = (unsigned short)lh[t * 8 + i];   // <=14.5k/block < 65536

    // ---- last-block election (release -> count -> acquire) ----
    __threadfence();
    if (t == 0) {
        unsigned old = atomicAdd(&ctrl[2], 1u);
        lastf = (old == HIST_BLOCKS - 1) ? 1 : 0;
    }
    __syncthreads();
    if (!lastf) return;
    __threadfence();

    // ---- cutoff scan (1024 threads of the last block) ----
    unsigned bsum[8];
#pragma unroll
    for (int i = 0; i < 8; ++i) bsum[i] = 0u;
    for (int p = 0; p < HIST_BLOCKS; ++p) {
        const unsigned short* hp = hist_part + (size_t)p * NBINS + t * 8;
#pragma unroll
        for (int i = 0; i < 8; ++i) bsum[i] += hp[i];   // 16 B/lane, coalesced
    }
    __syncthreads();   // everyone done with lh's histogram use
    unsigned s = 0;
#pragma unroll
    for (int i = 0; i < 8; ++i) { lh[t * 8 + i] = bsum[i]; s += bsum[i]; }
    pa[t] = s;
    __syncthreads();

    // inclusive suffix scan, ping-pong (10 barriers)
    unsigned int* srcb = pa; unsigned int* dstb = pb;
    for (int off = 1; off < 1024; off <<= 1) {
        unsigned v = srcb[t] + ((t + off < 1024) ? srcb[t + off] : 0u);
        dstb[t] = v;
        __syncthreads();
        unsigned int* tmp = srcb; srcb = dstb; dstb = tmp;
    }
    unsigned St = srcb[t];
    unsigned Sn = (t < 1023) ? srcb[t + 1] : 0u;

    if (t == 0) {
        ctrl[0] = 0u;                       // reset compact counter (next dispatch)
        if (St < TARGET) ctrl[1] = 0u;      // total < TARGET -> keep all valid
    }
    // unique crossing thread finds b* = max{b : suffix(b) >= TARGET}
    if (St >= TARGET && Sn < TARGET) {
        unsigned run = Sn;
#pragma unroll
        for (int i = 7; i >= 0; --i) {
            run += lh[t * 8 + i];
            if (run >= TARGET) { ctrl[1] = (unsigned)(t * 8 + i); break; }
        }
    }
}

// box decode for one candidate (matches reference formulas, fp32)
__device__ inline float4 decode_box(const float* __restrict__ feats,
                                    const float* __restrict__ anchors, int ci)
{
    int a = ci % 5;
    int cell = ci / 5;
    int gx = cell % 76;
    int gy = (cell / 76) % 76;
    const float* f = feats + (long long)ci * 85;
    float bx = (1.0f / (1.0f + __expf(-f[0])) + (float)gx) / 76.0f;
    float by = (1.0f / (1.0f + __expf(-f[1])) + (float)gy) / 76.0f;
    float bw = __expf(f[2]) * anchors[2 * a]     / 76.0f;
    float bh = __expf(f[3]) * anchors[2 * a + 1] / 76.0f;
    return make_float4(by - bh * 0.5f, bx - bw * 0.5f,
                       by + bh * 0.5f, bx + bw * 0.5f);  // y1,x1,y2,x2
}

// ============ Kernel 3: compact + (last block) sort-free greedy NMS ============
__global__ __launch_bounds__(1024) void compact_nms_kernel(
    const float* __restrict__ scores, unsigned int* __restrict__ ctrl,
    float* __restrict__ lscore, int* __restrict__ lidx,
    const float* __restrict__ feats, const float* __restrict__ anchors,
    const unsigned char* __restrict__ cls, float* __restrict__ out)
{
    __shared__ unsigned long long wkey[16];
    __shared__ unsigned long long bkey;
    __shared__ float4 bbox;
    __shared__ int lastf;
    const int t = threadIdx.x;
    const int i = blockIdx.x * CPB + t;

    // ---- compact phase ----
    if (i < N_CAND) {
        float sw = scores[i];
        if (sw >= SCORE_THR) {
            int bin = (int)(sw * (float)NBINS);
            bin = bin > (NBINS - 1) ? (NBINS - 1) : bin;
            if (bin >= (int)ctrl[1]) {
                unsigned pos = atomicAdd(&ctrl[0], 1u);
                if (pos < SMAX) { lscore[pos] = sw; lidx[pos] = i; }
            }
        }
    }
    __syncthreads();
    __threadfence();
    if (t == 0) {
        unsigned old = atomicAdd(&ctrl[3], 1u);
        lastf = (old == COMPACT_BLOCKS - 1) ? 1 : 0;
    }
    __syncthreads();
    if (!lastf) return;
    __threadfence();

    // ---- NMS phase (1024 threads, 1 candidate/thread) ----
    unsigned cnt = ctrl[0];
    int n = (cnt < (unsigned)SMAX) ? (int)cnt : SMAX;

    unsigned long long key = 0ull;
    float4 mb = make_float4(0.f, 0.f, 0.f, 0.f);
    float  msc = 0.f, mcls = 0.f;
    unsigned midx = 0xFFFFFFFFu;
    bool aliveb = false;
    if (t < n) {
        msc  = lscore[t];
        midx = (unsigned)lidx[t];
        key  = ((unsigned long long)__float_as_uint(msc) << 32)
             | (unsigned long long)(0xFFFFFFFFu - midx);   // score desc, idx asc
        mb   = decode_box(feats, anchors, (int)midx);
        mcls = (float)cls[midx];
        aliveb = true;
    }

    for (int r = 0; r < 10; ++r) {
        unsigned long long k0 = aliveb ? key : 0ull;
#pragma unroll
        for (int msk = 32; msk > 0; msk >>= 1) {
            unsigned long long o = __shfl_xor(k0, msk);
            k0 = (o > k0) ? o : k0;
        }
        if ((t & 63) == 0) wkey[t >> 6] = k0;
        __syncthreads();
        if (t < 16) {
            unsigned long long v = wkey[t];
#pragma unroll
            for (int msk = 8; msk > 0; msk >>= 1) {
                unsigned long long o = __shfl_xor(v, msk);
                v = (o > v) ? o : v;
            }
            if (t == 0) bkey = v;
        }
        __syncthreads();

        unsigned long long wk = bkey;
        bool have = (wk != 0ull);
        unsigned widx = have ? (0xFFFFFFFFu - (unsigned)(wk & 0xFFFFFFFFull)) : 0xFFFFFFFFu;

        if (have && aliveb && midx == widx) {   // unique winner thread
            bbox = mb;
            out[r * 6 + 0] = mb.x;
            out[r * 6 + 1] = mb.y;
            out[r * 6 + 2] = mb.z;
            out[r * 6 + 3] = mb.w;
            out[r * 6 + 4] = msc;
            out[r * 6 + 5] = mcls;
            aliveb = false;
        }
        if (!have && t == 0) {
#pragma unroll
            for (int q = 0; q < 6; ++q) out[r * 6 + q] = 0.f;
        }
        __syncthreads();                        // bbox visible to all

        if (have && aliveb) {
            float4 ab = bbox;
            float aarea = fmaxf(ab.z - ab.x, 0.f) * fmaxf(ab.w - ab.y, 0.f);
            float iy1 = fmaxf(ab.x, mb.x);
            float ix1 = fmaxf(ab.y, mb.y);
            float iy2 = fminf(ab.z, mb.z);
            float ix2 = fminf(ab.w, mb.w);
            float inter = fmaxf(iy2 - iy1, 0.f) * fmaxf(ix2 - ix1, 0.f);
            float carea = fmaxf(mb.z - mb.x, 0.f) * fmaxf(mb.w - mb.y, 0.f);
            float iou = inter / (aarea + carea - inter + 1e-9f);
            if (iou > 0.5f) aliveb = false;
        }
    }
}

extern "C" void kernel_launch(void* const* d_in, const int* in_sizes, int n_in,
                              void* d_out, int out_size, void* d_ws, size_t ws_size,
                              hipStream_t stream) {
    const float* feats   = (const float*)d_in[0];
    const float* anchors = (const float*)d_in[1];
    char* ws = (char*)d_ws;

    unsigned int*   ctrl      = (unsigned int*)(ws + 0);
    unsigned short* hist_part = (unsigned short*)(ws + 256);
    float*          lscore    = (float*)(ws + 524544);
    int*            lidx      = (int*)(ws + 528640);
    float*          scores    = (float*)(ws + 532736);
    unsigned char*  cls       = (unsigned char*)(ws + 2381056);
    float*          out       = (float*)d_out;

    decode_kernel      <<<N_CAND / 64, 64, 0, stream>>>(feats, scores, cls, ctrl);
    hist_cutoff_kernel <<<HIST_BLOCKS, 1024, 0, stream>>>(scores, hist_part, ctrl);
    compact_nms_kernel <<<COMPACT_BLOCKS, 1024, 0, stream>>>(scores, ctrl, lscore, lidx,
                                                             feats, anchors, cls, out);
}

// Round 10
// 59.642 us; speedup vs baseline: 3.0519x; 3.0519x over previous
//
#include <hip/hip_runtime.h>
#include <stdint.h>

#define N_CAND 462080   // 16*76*76*5
#define NBINS  2048
#define HIST_BLOCKS 32
#define COMPACT_BLOCKS 64
#define TARGET 256u
#define SMAX   1024
#define SCORE_THR 0.02f
// ctrl u32 indices, 64B apart (separate cache lines)
#define C_CNT 0    // compact count (hot atomic)
#define C_BIN 16   // cutoff bin
#define C_HD  32   // hist done-counter
#define C_CD  48   // compact done-counter

// ---------------- ws layout (bytes) ----------------
// ctrl      : 64 x u32       @ 0       end 256
// hist_part : 32 x 2048 u16  @ 256     end 131328
// lscore    : 1024 x f32     @ 131328  end 135424
// lidx      : 1024 x i32     @ 135424  end 139520
// scores    : N x f32        @ 139520  end 1987840
// cls       : N x u8         @ 1987840 end 2449920  (~2.45 MB)
// No memset dispatch: decode block 0 re-arms both done-counters every call;
// hist's elected block zeroes C_CNT and always writes C_BIN.
// => no dependence on initial ws content (harness poisons ws to 0xAA).

typedef const __attribute__((address_space(1))) uint32_t* gas1_u32;
typedef __attribute__((address_space(3))) uint32_t*       las3_u32;
#define GLOAD_LDS16(g, l) __builtin_amdgcn_global_load_lds( \
    (gas1_u32)(const void*)(g), (las3_u32)(void*)(l), 16, 0, 0)

// ============ Kernel 1: decode — one wave per block, no barriers ============
__global__ __launch_bounds__(64) void decode_kernel(
    const float* __restrict__ feats,
    float* __restrict__ scores, unsigned char* __restrict__ cls,
    unsigned int* __restrict__ ctrl)
{
    __shared__ __align__(16) float lds[64 * 85];   // 21760 B -> 7 blocks/CU
    const int t = threadIdx.x;                     // 0..63 (one wave)
    const long long base = (long long)blockIdx.x * 64;

    if (blockIdx.x == 0 && t == 0) { ctrl[C_HD] = 0u; ctrl[C_CD] = 0u; }  // re-arm

    // 64*85 floats = 1360 float4; 21 full wave-rounds + 16-lane tail.
    const float4* __restrict__ src = (const float4*)(feats + base * 85);
    float4* dst = (float4*)lds;
#pragma unroll
    for (int i = 0; i < 21; ++i)
        GLOAD_LDS16(src + i * 64 + t, dst + i * 64 + t);
    if (t < 16) GLOAD_LDS16(src + 21 * 64 + t, dst + 21 * 64 + t);

    asm volatile("s_waitcnt vmcnt(0)" ::: "memory");   // per-wave drain, no barrier
    __builtin_amdgcn_sched_barrier(0);

    const float* f = lds + t * 85;   // bank (t*21+k)%32: gcd(21,32)=1 -> conflict-free
    const int ci = (int)base + t;

    // class argmax over raw logits (== argmax of softmax, first-index ties)
    float m = f[5];
    int cbest = 0;
#pragma unroll
    for (int k = 1; k < 80; ++k) {
        float v = f[5 + k];
        if (v > m) { m = v; cbest = k; }
    }
    // softmax max-prob = 1 / sum(exp(l - m))
    float s0 = 0.f, s1 = 0.f, s2 = 0.f, s3 = 0.f;
#pragma unroll
    for (int k = 0; k < 80; k += 4) {
        s0 += __expf(f[5 + k] - m);
        s1 += __expf(f[6 + k] - m);
        s2 += __expf(f[7 + k] - m);
        s3 += __expf(f[8 + k] - m);
    }
    float ssum = (s0 + s1) + (s2 + s3);
    float conf = 1.0f / (1.0f + __expf(-f[4]));
    float score = conf * (1.0f / ssum);

    cls[ci] = (unsigned char)cbest;
    scores[ci] = (score >= SCORE_THR) ? score : -1.0f;
}

// ============ Kernel 2: histogram + (elected last block) cutoff scan ============
// Fences are t0-only: __syncthreads() drains vmcnt per wave, so all block
// stores are complete in this CU's XCD L2; one t0 __threadfence (wbl2) makes
// them globally visible before the election atomic. Elected block t0-fences
// (invalidate) after winning, then barrier, then reads.
__global__ __launch_bounds__(1024) void hist_cutoff_kernel(
    const float* __restrict__ scores, unsigned short* __restrict__ hist_part,
    unsigned int* __restrict__ ctrl)
{
    __shared__ unsigned int lh[NBINS];          // 8 KB
    __shared__ unsigned int pa[1024], pb[1024]; // 8 KB ping-pong
    __shared__ int lastf;
    const int t = threadIdx.x;

    lh[2 * t] = 0u; lh[2 * t + 1] = 0u;
    __syncthreads();

    for (int i = blockIdx.x * 1024 + t; i < N_CAND; i += HIST_BLOCKS * 1024) {
        float s = scores[i];
        if (s >= SCORE_THR) {
            int bin = (int)(s * (float)NBINS);
            bin = bin > (NBINS - 1) ? (NBINS - 1) : bin;
            atomicAdd(&lh[bin], 1u);   // LDS atomic only
        }
    }
    __syncthreads();
    // store part as packed u32 (two u16 bins), coalesced
    unsigned int* outp = (unsigned int*)(hist_part + (size_t)blockIdx.x * NBINS);
    outp[t] = (lh[2 * t] & 0xFFFFu) | (lh[2 * t + 1] << 16);
    __syncthreads();                                   // vmcnt drained -> stores in L2

    if (t == 0) {
        __threadfence();                               // release: wb this XCD's L2
        unsigned old = atomicAdd(&ctrl[C_HD], 1u);
        lastf = (old == HIST_BLOCKS - 1) ? 1 : 0;
    }
    __syncthreads();
    if (!lastf) return;
    if (t == 0) __threadfence();                       // acquire: invalidate caches
    __syncthreads();

    // ---- cutoff scan (elected block) ----
    const unsigned int* hp32 = (const unsigned int*)hist_part;
    unsigned b0 = 0u, b1 = 0u;
#pragma unroll 4
    for (int p = 0; p < HIST_BLOCKS; ++p) {
        unsigned v = hp32[p * 1024 + t];
        b0 += v & 0xFFFFu;
        b1 += v >> 16;
    }
    lh[2 * t] = b0; lh[2 * t + 1] = b1;
    pa[t] = b0 + b1;
    __syncthreads();

    // inclusive suffix scan, ping-pong (10 barriers)
    unsigned int* srcb = pa; unsigned int* dstb = pb;
    for (int off = 1; off < 1024; off <<= 1) {
        unsigned v = srcb[t] + ((t + off < 1024) ? srcb[t + off] : 0u);
        dstb[t] = v;
        __syncthreads();
        unsigned int* tmp = srcb; srcb = dstb; dstb = tmp;
    }
    unsigned St = srcb[t];
    unsigned Sn = (t < 1023) ? srcb[t + 1] : 0u;

    if (t == 0) {
        ctrl[C_CNT] = 0u;                   // reset compact counter (next dispatch)
        if (St < TARGET) ctrl[C_BIN] = 0u;  // total < TARGET -> keep all valid
    }
    // unique crossing thread: b* = max{b : suffix(b) >= TARGET}
    if (St >= TARGET && Sn < TARGET) {
        unsigned run = Sn + lh[2 * t + 1];
        ctrl[C_BIN] = (run >= TARGET) ? (unsigned)(2 * t + 1) : (unsigned)(2 * t);
    }
}

// box decode for one candidate (matches reference formulas, fp32)
__device__ inline float4 decode_box(const float* __restrict__ feats,
                                    const float* __restrict__ anchors, int ci)
{
    int a = ci % 5;
    int cell = ci / 5;
    int gx = cell % 76;
    int gy = (cell / 76) % 76;
    const float* f = feats + (long long)ci * 85;
    float bx = (1.0f / (1.0f + __expf(-f[0])) + (float)gx) / 76.0f;
    float by = (1.0f / (1.0f + __expf(-f[1])) + (float)gy) / 76.0f;
    float bw = __expf(f[2]) * anchors[2 * a]     / 76.0f;
    float bh = __expf(f[3]) * anchors[2 * a + 1] / 76.0f;
    return make_float4(by - bh * 0.5f, bx - bw * 0.5f,
                       by + bh * 0.5f, bx + bw * 0.5f);  // y1,x1,y2,x2
}

// ============ Kernel 3: compact (64-block grid-stride) + elected NMS ============
__global__ __launch_bounds__(1024) void compact_nms_kernel(
    const float* __restrict__ scores, unsigned int* __restrict__ ctrl,
    float* __restrict__ lscore, int* __restrict__ lidx,
    const float* __restrict__ feats, const float* __restrict__ anchors,
    const unsigned char* __restrict__ cls, float* __restrict__ out)
{
    __shared__ unsigned long long wkey[16];
    __shared__ unsigned long long bkey;
    __shared__ float4 bbox;
    __shared__ int lastf;
    const int t = threadIdx.x;

    // ---- compact phase (grid-stride) ----
    const int cut = (int)ctrl[C_BIN];   // written by previous dispatch: coherent
    for (int i = blockIdx.x * 1024 + t; i < N_CAND; i += COMPACT_BLOCKS * 1024) {
        float sw = scores[i];
        if (sw >= SCORE_THR) {
            int bin = (int)(sw * (float)NBINS);
            bin = bin > (NBINS - 1) ? (NBINS - 1) : bin;
            if (bin >= cut) {
                unsigned pos = atomicAdd(&ctrl[C_CNT], 1u);
                if (pos < SMAX) { lscore[pos] = sw; lidx[pos] = i; }
            }
        }
    }
    __syncthreads();                                   // vmcnt drained -> stores in L2
    if (t == 0) {
        __threadfence();                               // release
        unsigned old = atomicAdd(&ctrl[C_CD], 1u);
        lastf = (old == COMPACT_BLOCKS - 1) ? 1 : 0;
    }
    __syncthreads();
    if (!lastf) return;
    if (t == 0) __threadfence();                       // acquire
    __syncthreads();

    // ---- NMS phase (1024 threads, 1 candidate/thread) ----
    unsigned cnt = ctrl[C_CNT];
    int n = (cnt < (unsigned)SMAX) ? (int)cnt : SMAX;

    unsigned long long key = 0ull;
    float4 mb = make_float4(0.f, 0.f, 0.f, 0.f);
    float  msc = 0.f, mcls = 0.f;
    unsigned midx = 0xFFFFFFFFu;
    bool aliveb = false;
    if (t < n) {
        msc  = lscore[t];
        midx = (unsigned)lidx[t];
        key  = ((unsigned long long)__float_as_uint(msc) << 32)
             | (unsigned long long)(0xFFFFFFFFu - midx);   // score desc, idx asc
        mb   = decode_box(feats, anchors, (int)midx);
        mcls = (float)cls[midx];
        aliveb = true;
    }

    for (int r = 0; r < 10; ++r) {
        unsigned long long k0 = aliveb ? key : 0ull;
#pragma unroll
        for (int msk = 32; msk > 0; msk >>= 1) {
            unsigned long long o = __shfl_xor(k0, msk);
            k0 = (o > k0) ? o : k0;
        }
        if ((t & 63) == 0) wkey[t >> 6] = k0;
        __syncthreads();
        if (t < 16) {
            unsigned long long v = wkey[t];
#pragma unroll
            for (int msk = 8; msk > 0; msk >>= 1) {
                unsigned long long o = __shfl_xor(v, msk);
                v = (o > v) ? o : v;
            }
            if (t == 0) bkey = v;
        }
        __syncthreads();

        unsigned long long wk = bkey;
        bool have = (wk != 0ull);
        unsigned widx = have ? (0xFFFFFFFFu - (unsigned)(wk & 0xFFFFFFFFull)) : 0xFFFFFFFFu;

        if (have && aliveb && midx == widx) {   // unique winner thread
            bbox = mb;
            out[r * 6 + 0] = mb.x;
            out[r * 6 + 1] = mb.y;
            out[r * 6 + 2] = mb.z;
            out[r * 6 + 3] = mb.w;
            out[r * 6 + 4] = msc;
            out[r * 6 + 5] = mcls;
            aliveb = false;
        }
        if (!have && t == 0) {
#pragma unroll
            for (int q = 0; q < 6; ++q) out[r * 6 + q] = 0.f;
        }
        __syncthreads();                        // bbox visible to all

        if (have && aliveb) {
            float4 ab = bbox;
            float aarea = fmaxf(ab.z - ab.x, 0.f) * fmaxf(ab.w - ab.y, 0.f);
            float iy1 = fmaxf(ab.x, mb.x);
            float ix1 = fmaxf(ab.y, mb.y);
            float iy2 = fminf(ab.z, mb.z);
            float ix2 = fminf(ab.w, mb.w);
            float inter = fmaxf(iy2 - iy1, 0.f) * fmaxf(ix2 - ix1, 0.f);
            float carea = fmaxf(mb.z - mb.x, 0.f) * fmaxf(mb.w - mb.y, 0.f);
            float iou = inter / (aarea + carea - inter + 1e-9f);
            if (iou > 0.5f) aliveb = false;
        }
    }
}

extern "C" void kernel_launch(void* const* d_in, const int* in_sizes, int n_in,
                              void* d_out, int out_size, void* d_ws, size_t ws_size,
                              hipStream_t stream) {
    const float* feats   = (const float*)d_in[0];
    const float* anchors = (const float*)d_in[1];
    char* ws = (char*)d_ws;

    unsigned int*   ctrl      = (unsigned int*)(ws + 0);
    unsigned short* hist_part = (unsigned short*)(ws + 256);
    float*          lscore    = (float*)(ws + 131328);
    int*            lidx      = (int*)(ws + 135424);
    float*          scores    = (float*)(ws + 139520);
    unsigned char*  cls       = (unsigned char*)(ws + 1987840);
    float*          out       = (float*)d_out;

    decode_kernel      <<<N_CAND / 64, 64, 0, stream>>>(feats, scores, cls, ctrl);
    hist_cutoff_kernel <<<HIST_BLOCKS, 1024, 0, stream>>>(scores, hist_part, ctrl);
    compact_nms_kernel <<<COMPACT_BLOCKS, 1024, 0, stream>>>(scores, ctrl, lscore, lidx,
                                                             feats, anchors, cls, out);
}